// Round 18
// baseline (82.334 us; speedup 1.0000x reference)
//
#include <hip/hip_runtime.h>

namespace {

constexpr int kB = 256;
constexpr int kS = 512;
constexpr int CHUNK  = 30;                        // useful frames per wave (32 lane-pairs, 2 overlap)
constexpr int NCHUNK = (kS + CHUNK - 1) / CHUNK;  // 18
constexpr int NSLOT  = 64;
// Linear half-phase buffer: [par][32 frames][9 float2] = 576 float2 = 4608 B.
constexpr int LDSF   = 1152;                      // floats

// lambda / count constants as inline literals (zero register cost).
constexpr float BSf   = 131072.f;                 // kB*kS
constexpr float K_R1  = 5.0f / (2.f * BSf * 3.f);
constexpr float K_R2  = 5.0f / (2.f * BSf * 6.f);
constexpr float K_ROT = 1.0f / (2.f * BSf * 120.f);
constexpr float K_POS = 2.0f / (2.f * BSf * 66.f);
constexpr float K_VEL = 1.0f / (2.f * 256.f * 511.f * 66.f);
constexpr float K_SMO = 0.5f / (2.f * 256.f * 510.f * 66.f);
constexpr float K_FLO = 2.0f / (2.f * BSf * 2.f);
constexpr float K_CON = 2.0f / (256.f * 511.f * 2.f);   // even lanes only (no 2x)
constexpr float K_TIL = 1.0f / (2.f * BSf * 3.f);

__device__ __forceinline__ void cont6d(const float a[6], float R[3][3]) {
    float n1 = a[0]*a[0] + a[1]*a[1] + a[2]*a[2];
    float i1 = __frsqrt_rn(fmaxf(n1, 1e-24f));
    float b1x = a[0]*i1, b1y = a[1]*i1, b1z = a[2]*i1;
    float dp  = b1x*a[3] + b1y*a[4] + b1z*a[5];
    float ux = a[3] - b1x*dp, uy = a[4] - b1y*dp, uz = a[5] - b1z*dp;
    float n2 = ux*ux + uy*uy + uz*uz;
    float i2 = __frsqrt_rn(fmaxf(n2, 1e-24f));
    float b2x = ux*i2, b2y = uy*i2, b2z = uz*i2;
    R[0][0] = b1x; R[1][0] = b1y; R[2][0] = b1z;
    R[0][1] = b2x; R[1][1] = b2y; R[2][1] = b2z;
    R[0][2] = b1y*b2z - b1z*b2y;
    R[1][2] = b1z*b2x - b1x*b2z;
    R[2][2] = b1x*b2y - b1y*b2x;
}

// Coalesced global -> LDS half-phase stage with LINEAR LDS writes.
// C2 = float2 per frame per tensor (9 normal, 3 for the last joint).
template<int C2, int FB>
__device__ __forceinline__ void stage(const float* __restrict__ pred,
                                      const float* __restrict__ targ,
                                      size_t rowbase, int s0,
                                      float* __restrict__ ldsw, int lane) {
    constexpr int V = 32 * C2;           // float2 elements per tensor
    constexpr int R = (2 * V) / 64;      // V in {288,96} -> R in {9,3}
    const float* pp_ = pred + rowbase * 132 + FB;
    const float* tp_ = targ + rowbase * 132 + FB;
    float2 st[9];
    #pragma unroll
    for (int r = 0; r < R; ++r) {
        int u = r * 64 + lane;
        int par2 = (u >= V) ? 1 : 0;
        int uu = u - par2 * V;
        int f = uu / C2;                 // magic-mul (C2 compile-time)
        int c = uu - f * C2;
        int sf = s0 + f; sf = (sf < kS) ? sf : (kS - 1);
        const float* bp = par2 ? tp_ : pp_;
        st[r] = *reinterpret_cast<const float2*>(bp + (size_t)sf * 132 + 2 * c);
    }
    float2* l2 = reinterpret_cast<float2*>(ldsw);
    #pragma unroll
    for (int r = 0; r < R; ++r)
        l2[r * 64 + lane] = st[r];       // base + imm, zero write math
}

__device__ __forceinline__ void read6(const float* __restrict__ row, int jj, float a[6]) {
    const float2* q = reinterpret_cast<const float2*>(row + 6 * jj);
    float2 x = q[0], y = q[1], z = q[2];
    a[0]=x.x; a[1]=x.y; a[2]=y.x; a[3]=y.y; a[4]=z.x; a[5]=z.y;
}

// One FK joint (r12 body: partner row from LDS, cross-frame via shfl_down).
template<bool NEED_R, bool SPINE_J, bool FOOT>
__device__ __forceinline__ void joint_step(
    const float a[6], const float ap[6], const float* __restrict__ off,
    const float Rp[3][3], const float pp[3],
    float Rn[3][3], float pn[3],
    float wf, float wv, float wa, int par, float& s)
{
    float dsum = 0.f;
    #pragma unroll
    for (int k = 0; k < 6; ++k) { float d = a[k] - ap[k]; dsum += d*d; }
    s += wf * (K_ROT * dsum);

    const float ox = off[0], oy = off[1], oz = off[2];
    #pragma unroll
    for (int r = 0; r < 3; ++r)
        pn[r] = pp[r] + Rp[r][0]*ox + Rp[r][1]*oy + Rp[r][2]*oz;

    if constexpr (NEED_R) {
        float Rl[3][3];
        cont6d(a, Rl);
        if constexpr (SPINE_J) {
            float t0 = Rl[0][1] - __shfl_xor(Rl[0][1], 1);
            float t1 = Rl[1][1] - __shfl_xor(Rl[1][1], 1);
            float t2 = Rl[2][1] - __shfl_xor(Rl[2][1], 1);
            s += wf * (K_TIL * (t0*t0 + t1*t1 + t2*t2));
        }
        #pragma unroll
        for (int r = 0; r < 3; ++r)
            #pragma unroll
            for (int c = 0; c < 3; ++c)
                Rn[r][c] = Rp[r][0]*Rl[0][c] + Rp[r][1]*Rl[1][c] + Rp[r][2]*Rl[2][c];
    }

    float d[3];
    #pragma unroll
    for (int r = 0; r < 3; ++r) d[r] = pn[r] - __shfl_xor(pn[r], 1);
    s += wf * (K_POS * (d[0]*d[0] + d[1]*d[1] + d[2]*d[2]));

    float va = 0.f, sa = 0.f;
    #pragma unroll
    for (int r = 0; r < 3; ++r) {
        float d1 = __shfl_down(d[r], 2);
        float d2 = __shfl_down(d[r], 4);
        float dv = d1 - d[r];            va += dv*dv;
        float ds = d2 - 2.f*d1 + d[r];   sa += ds*ds;
    }
    s += wv * (K_VEL * va);
    s += wa * (K_SMO * sa);

    if constexpr (FOOT) {
        s += wf * (K_FLO * (d[1]*d[1]));
        float vx = __shfl_down(pn[0], 2) - pn[0];
        float vy = __shfl_down(pn[1], 2) - pn[1];
        float vz = __shfl_down(pn[2], 2) - pn[2];
        float gx = __shfl_xor(vx, 1);
        float gy = __shfl_xor(vy, 1);
        float gz = __shfl_xor(vz, 1);
        float planted = (gx*gx + gy*gy + gz*gz < 2.5e-5f) ? 1.f : 0.f;
        float wc = (par == 0) ? wv : 0.f;
        s += wc * (K_CON * (planted * sqrtf(vx*vx + vy*vy + vz*vz)));
    }
}

// r17 linear-staging body, 8 HALF-phases (3 joints each): LDS/WG halves to
// 4608 B — decisive test of the "~550 KB LDS allocated per us" WG-throughput
// model (dur pred ~40-48 us if right; >=70 if wrong).
// NO occupancy hints (compiler VGPR caps <136 spill: r2/r4/r6/r8).
__global__ __launch_bounds__(64)
void motion_loss_kernel(const float* __restrict__ pred,
                        const float* __restrict__ targ,
                        const float* __restrict__ offs,
                        float* __restrict__ acc)
{
    __shared__ float lds[LDSF];

    const int lane = threadIdx.x;
    const int fid  = lane >> 1;         // frame-in-chunk 0..31
    const int par  = lane & 1;          // 0 = pred, 1 = targ

    const int cg    = blockIdx.x;                 // chunk id, 0..4607
    const int b     = cg / NCHUNK;
    const int chunk = cg - b * NCHUNK;
    const int s0    = chunk * CHUNK;
    const int s     = s0 + fid;
    const size_t rowbase = (size_t)b * kS;

    const float wf = (fid < CHUNK && s     < kS) ? 1.f : 0.f;
    const float wv = (fid < CHUNK && s + 1 < kS) ? 1.f : 0.f;
    const float wa = (fid < CHUNK && s + 2 < kS) ? 1.f : 0.f;

    // per-lane read bases: C2=9 layout (stages 0..6), C2=3 layout (stage 7)
    const float* ldsr9 = lds + (par       * 288 + fid * 9) * 2;
    const float* ldsp9 = lds + ((par ^ 1) * 288 + fid * 9) * 2;
    const float* ldsr3 = lds + (par       *  96 + fid * 3) * 2;
    const float* ldsp3 = lds + ((par ^ 1) *  96 + fid * 3) * 2;

    float loss = 0.f;
    float R1[3][3], R3[3][3], RA[3][3], RB[3][3];
    float p1[3], p3[3], pA[3], pB[3], pS[3];

    #define JS(LR, LP, J, JJ, NR, SP, FT, RP, PP, RN, PN) { \
        float a_[6], ap_[6]; read6(LR, JJ, a_); read6(LP, JJ, ap_); \
        joint_step<NR, SP, FT>(a_, ap_, offs + (J)*3, RP, PP, RN, PN, \
                               wf, wv, wa, par, loss); }

    #define SB __builtin_amdgcn_sched_barrier(0)

    // ---- stage 0: joints 0..2 (floats 0..18) ----
    stage<9, 0>(pred, targ, rowbase, s0, lds, lane);
    { // joint 0: root channels 0..2; positions identically 0
        float d0 = ldsr9[0] - ldsp9[0];
        float d1 = ldsr9[1] - ldsp9[1];
        float d2 = ldsr9[2] - ldsp9[2];
        loss += wf * (K_R1 * (d0*d0 + d1*d1 + d2*d2));
    }
    { // joint 1: parent identity; pos = offs[1] for both (pos losses cancel)
        float a_[6], ap_[6];
        read6(ldsr9, 1, a_); read6(ldsp9, 1, ap_);
        float dsum = 0.f;
        #pragma unroll
        for (int k = 0; k < 6; ++k) { float d = a_[k] - ap_[k]; dsum += d*d; }
        loss += wf * (K_R2 * dsum);
        cont6d(a_, R1);
        p1[0] = offs[3]; p1[1] = offs[4]; p1[2] = offs[5];
    }
    JS(ldsr9, ldsp9,  2, 2, true , true , false, R1, p1, RA, pA);   // spine

    // ---- stage 1: joints 3..5 (floats 18..36) ----
    SB; stage<9, 18>(pred, targ, rowbase, s0, lds, lane);
    JS(ldsr9, ldsp9,  3, 0, true , false, false, RA, pA, R3, p3);
    JS(ldsr9, ldsp9,  4, 1, true , false, false, R3, p3, RA, pA);
    JS(ldsr9, ldsp9,  5, 2, false, false, false, RA, pA, RB, pS);   // leaf

    // ---- stage 2: joints 6..8 (floats 36..54) ----
    SB; stage<9, 36>(pred, targ, rowbase, s0, lds, lane);
    JS(ldsr9, ldsp9,  6, 0, true , false, false, R3, p3, RA, pA);
    JS(ldsr9, ldsp9,  7, 1, true , false, false, RA, pA, RB, pB);
    JS(ldsr9, ldsp9,  8, 2, true , false, false, RB, pB, RA, pA);

    // ---- stage 3: joints 9..11 (floats 54..72) ----
    SB; stage<9, 54>(pred, targ, rowbase, s0, lds, lane);
    JS(ldsr9, ldsp9,  9, 0, false, false, false, RA, pA, RB, pS);   // leaf
    JS(ldsr9, ldsp9, 10, 1, true , false, false, R3, p3, RB, pB);   // R3 dies
    JS(ldsr9, ldsp9, 11, 2, true , false, false, RB, pB, RA, pA);

    // ---- stage 4: joints 12..14 (floats 72..90) ----
    SB; stage<9, 72>(pred, targ, rowbase, s0, lds, lane);
    JS(ldsr9, ldsp9, 12, 0, true , false, false, RA, pA, RB, pB);
    JS(ldsr9, ldsp9, 13, 1, false, false, false, RB, pB, RA, pS);   // leaf
    JS(ldsr9, ldsp9, 14, 2, true , false, false, R1, p1, RA, pA);

    // ---- stage 5: joints 15..17 (floats 90..108) ----
    SB; stage<9, 90>(pred, targ, rowbase, s0, lds, lane);
    JS(ldsr9, ldsp9, 15, 0, true , false, false, RA, pA, RB, pB);
    JS(ldsr9, ldsp9, 16, 1, true , false, false, RB, pB, RA, pA);
    JS(ldsr9, ldsp9, 17, 2, true , false, false, RA, pA, RB, pB);

    // ---- stage 6: joints 18..20 (floats 108..126) ----
    SB; stage<9, 108>(pred, targ, rowbase, s0, lds, lane);
    JS(ldsr9, ldsp9, 18, 0, false, false, true , RB, pB, RA, pS);   // FOOT leaf
    JS(ldsr9, ldsp9, 19, 1, true , false, false, R1, p1, RA, pA);   // R1 dies
    JS(ldsr9, ldsp9, 20, 2, true , false, false, RA, pA, RB, pB);

    // ---- stage 7: joint 21 (floats 126..132) ----
    SB; stage<3, 126>(pred, targ, rowbase, s0, lds, lane);
    JS(ldsr3, ldsp3, 21, 0, false, false, true , RB, pB, RA, pS);   // FOOT leaf
    #undef JS
    #undef SB

    // wave butterfly reduce; one atomic per wave, spread over 64 slots
    float v = loss;
    #pragma unroll
    for (int o = 32; o > 0; o >>= 1) v += __shfl_xor(v, o);
    if (lane == 0) atomicAdd(&acc[cg & (NSLOT - 1)], v);
}

__global__ void finalize_kernel(const float* __restrict__ acc, float* __restrict__ out) {
    float v = acc[threadIdx.x];
    #pragma unroll
    for (int o = 32; o > 0; o >>= 1) v += __shfl_xor(v, o);
    if (threadIdx.x == 0) out[0] = v;
}

} // namespace

extern "C" void kernel_launch(void* const* d_in, const int* in_sizes, int n_in,
                              void* d_out, int out_size, void* d_ws, size_t ws_size,
                              hipStream_t stream) {
    const float* pred = (const float*)d_in[0];
    const float* targ = (const float*)d_in[1];
    const float* offs = (const float*)d_in[2];
    float* acc = (float*)d_ws;

    hipMemsetAsync(acc, 0, NSLOT * sizeof(float), stream);
    motion_loss_kernel<<<dim3(kB * NCHUNK), dim3(64), 0, stream>>>(pred, targ, offs, acc);
    finalize_kernel<<<1, 64, 0, stream>>>(acc, (float*)d_out);
}

// Round 19
// 64.710 us; speedup vs baseline: 1.2723x; 1.2723x over previous
//
#include <hip/hip_runtime.h>

namespace {

constexpr int kB = 256;
constexpr int kS = 512;
constexpr int CHUNK  = 62;                        // useful frames per wave (lane = frame, 2 overlap)
constexpr int NCHUNK = (kS + CHUNK - 1) / CHUNK;  // 9
constexpr int NSLOT  = 64;
constexpr int LDSF   = 2304;                      // floats: 1152 float2 = 9216 B

// lambda / count literals -- single-count (each frame term computed ONCE).
constexpr float BSf   = 131072.f;                 // kB*kS
constexpr float K_R1  = 5.0f / (BSf * 3.f);
constexpr float K_R2  = 5.0f / (BSf * 6.f);
constexpr float K_ROT = 1.0f / (BSf * 120.f);
constexpr float K_POS = 2.0f / (BSf * 66.f);
constexpr float K_VEL = 1.0f / (256.f * 511.f * 66.f);
constexpr float K_SMO = 0.5f / (256.f * 510.f * 66.f);
constexpr float K_FLO = 2.0f / (BSf * 2.f);
constexpr float K_CON = 2.0f / (256.f * 511.f * 2.f);
constexpr float K_TIL = 1.0f / (BSf * 3.f);

__device__ __forceinline__ void cont6d(const float a[6], float R[3][3]) {
    float n1 = a[0]*a[0] + a[1]*a[1] + a[2]*a[2];
    float i1 = __frsqrt_rn(fmaxf(n1, 1e-24f));
    float b1x = a[0]*i1, b1y = a[1]*i1, b1z = a[2]*i1;
    float dp  = b1x*a[3] + b1y*a[4] + b1z*a[5];
    float ux = a[3] - b1x*dp, uy = a[4] - b1y*dp, uz = a[5] - b1z*dp;
    float n2 = ux*ux + uy*uy + uz*uz;
    float i2 = __frsqrt_rn(fmaxf(n2, 1e-24f));
    float b2x = ux*i2, b2y = uy*i2, b2z = uz*i2;
    R[0][0] = b1x; R[1][0] = b1y; R[2][0] = b1z;
    R[0][1] = b2x; R[1][1] = b2y; R[2][1] = b2z;
    R[0][2] = b1y*b2z - b1z*b2y;
    R[1][2] = b1z*b2x - b1x*b2z;
    R[2][2] = b1x*b2y - b1y*b2x;
}

// Coalesced global -> LDS stage, LINEAR LDS writes. Both tensors, 64 frames.
// C2 = float2 per frame per tensor (9 normal stages, 3 for joint 21).
template<int C2, int FB>
__device__ __forceinline__ void stage(const float* __restrict__ pred,
                                      const float* __restrict__ targ,
                                      size_t rowbase, int s0,
                                      float* __restrict__ ldsw, int lane) {
    constexpr int V = 64 * C2;           // float2 per tensor
    constexpr int R = (2 * V) / 64;      // 2*C2: 18 or 6
    const float* pp_ = pred + rowbase * 132 + FB;
    const float* tp_ = targ + rowbase * 132 + FB;
    float2 st[18];
    #pragma unroll
    for (int r = 0; r < R; ++r) {
        int u = r * 64 + lane;
        int t2 = (u >= V) ? 1 : 0;
        int uu = u - t2 * V;
        int f = uu / C2;                 // magic-mul (compile-time C2)
        int c = uu - f * C2;
        int sf = s0 + f; sf = (sf < kS) ? sf : (kS - 1);
        const float* bp = t2 ? tp_ : pp_;
        st[r] = *reinterpret_cast<const float2*>(bp + (size_t)sf * 132 + 2 * c);
    }
    float2* l2 = reinterpret_cast<float2*>(ldsw);
    #pragma unroll
    for (int r = 0; r < R; ++r)
        l2[r * 64 + lane] = st[r];       // base + imm, zero write math
}

__device__ __forceinline__ void read6f(const float2* __restrict__ b, int jj, float a[6]) {
    float2 x = b[jj*3], y = b[jj*3+1], z = b[jj*3+2];
    a[0]=x.x; a[1]=x.y; a[2]=y.x; a[3]=y.y; a[4]=z.x; a[5]=z.y;
}

// One FK joint, BOTH skeletons in-lane. Cross-lane only for vel/smooth
// (shfl_down by 1/2 -- lane = frame). All diffs local.
template<bool NEED_R, bool SPINE_J, bool FOOT>
__device__ __forceinline__ void joint_step(
    const float aP[6], const float aT[6], const float* __restrict__ off,
    const float RpP[3][3], const float ppP[3], float RnP[3][3], float pnP[3],
    const float RpT[3][3], const float ppT[3], float RnT[3][3], float pnT[3],
    float wf, float wv, float wa, float& s)
{
    float dsum = 0.f;
    #pragma unroll
    for (int k = 0; k < 6; ++k) { float dd = aP[k] - aT[k]; dsum += dd*dd; }
    s += wf * (K_ROT * dsum);

    const float ox = off[0], oy = off[1], oz = off[2];
    #pragma unroll
    for (int r = 0; r < 3; ++r) {
        pnP[r] = ppP[r] + RpP[r][0]*ox + RpP[r][1]*oy + RpP[r][2]*oz;
        pnT[r] = ppT[r] + RpT[r][0]*ox + RpT[r][1]*oy + RpT[r][2]*oz;
    }

    if constexpr (NEED_R) {
        float RlP[3][3], RlT[3][3];
        cont6d(aP, RlP);
        cont6d(aT, RlT);
        if constexpr (SPINE_J) {
            float t0 = RlP[0][1] - RlT[0][1];
            float t1 = RlP[1][1] - RlT[1][1];
            float t2 = RlP[2][1] - RlT[2][1];
            s += wf * (K_TIL * (t0*t0 + t1*t1 + t2*t2));
        }
        #pragma unroll
        for (int r = 0; r < 3; ++r)
            #pragma unroll
            for (int c = 0; c < 3; ++c) {
                RnP[r][c] = RpP[r][0]*RlP[0][c] + RpP[r][1]*RlP[1][c] + RpP[r][2]*RlP[2][c];
                RnT[r][c] = RpT[r][0]*RlT[0][c] + RpT[r][1]*RlT[1][c] + RpT[r][2]*RlT[2][c];
            }
    }

    float d[3], d1[3];
    #pragma unroll
    for (int r = 0; r < 3; ++r) d[r] = pnP[r] - pnT[r];
    s += wf * (K_POS * (d[0]*d[0] + d[1]*d[1] + d[2]*d[2]));

    float va = 0.f, sa = 0.f;
    #pragma unroll
    for (int r = 0; r < 3; ++r) {
        d1[r]    = __shfl_down(d[r], 1);
        float d2 = __shfl_down(d[r], 2);
        float dv = d1[r] - d[r];            va += dv*dv;
        float ds = d2 - 2.f*d1[r] + d[r];   sa += ds*ds;
    }
    s += wv * (K_VEL * va);
    s += wa * (K_SMO * sa);

    if constexpr (FOOT) {
        s += wf * (K_FLO * (d[1]*d[1]));
        float gx = __shfl_down(pnT[0], 1) - pnT[0];   // gt foot velocity
        float gy = __shfl_down(pnT[1], 1) - pnT[1];
        float gz = __shfl_down(pnT[2], 1) - pnT[2];
        float pvx = gx + (d1[0] - d[0]);              // pred vel = gt vel + delta-d
        float pvy = gy + (d1[1] - d[1]);
        float pvz = gz + (d1[2] - d[2]);
        float planted = (gx*gx + gy*gy + gz*gz < 2.5e-5f) ? 1.f : 0.f;
        s += wv * (K_CON * (planted * sqrtf(pvx*pvx + pvy*pvy + pvz*pvz)));
    }
}

// Dual-skeleton lane=frame: 2304 waves (half of r12) -- attacks the observed
// ~55-66 waves/us delivery ceiling. In-lane diffs kill the pair-shuffles.
// NO occupancy hints (compiler VGPR caps below natural spill: r2/r4/r6/r8).
__global__ __launch_bounds__(64)
void motion_loss_kernel(const float* __restrict__ pred,
                        const float* __restrict__ targ,
                        const float* __restrict__ offs,
                        float* __restrict__ acc)
{
    __shared__ float lds[LDSF];

    const int lane = threadIdx.x;       // lane = frame-in-chunk
    const int cg    = blockIdx.x;                 // 0..2303
    const int b     = cg / NCHUNK;
    const int chunk = cg - b * NCHUNK;
    const int s0    = chunk * CHUNK;
    const int s     = s0 + lane;
    const size_t rowbase = (size_t)b * kS;

    const float wf = (lane < CHUNK && s     < kS) ? 1.f : 0.f;
    const float wv = (lane < CHUNK && s + 1 < kS) ? 1.f : 0.f;
    const float wa = (lane < CHUNK && s + 2 < kS) ? 1.f : 0.f;

    float2* l2 = reinterpret_cast<float2*>(lds);
    const float2* pb9 = l2 + lane * 9;            // own frame, pred, C2=9 layout
    const float2* tb9 = l2 + 576 + lane * 9;      // own frame, targ

    float loss = 0.f;

    // FK state, both chains. p1 is IDENTICAL for both (shared).
    float R1P[3][3], R3P[3][3], RAP[3][3], RBP[3][3];
    float R1T[3][3], R3T[3][3], RAT[3][3], RBT[3][3];
    float p1[3], p3P[3], pAP[3], pBP[3], pSP[3];
    float          p3T[3], pAT[3], pBT[3], pST[3];
    auto& p1P = p1; auto& p1T = p1;

    #define JS(J, JJ, NR, SP, FT, RP, PP, RN, PN) { \
        float aP_[6], aT_[6]; read6f(pb9, JJ, aP_); read6f(tb9, JJ, aT_); \
        joint_step<NR, SP, FT>(aP_, aT_, offs + (J)*3, \
            RP##P, PP##P, RN##P, PN##P, RP##T, PP##T, RN##T, PN##T, \
            wf, wv, wa, loss); }
    #define SB __builtin_amdgcn_sched_barrier(0)

    // ---- stage 0: joints 0..2 (floats 0..18) ----
    stage<9, 0>(pred, targ, rowbase, s0, lds, lane);
    { // joint 0: root channels 0..2 (in-lane diff); positions identically 0
        float aP_[6], aT_[6];
        read6f(pb9, 0, aP_); read6f(tb9, 0, aT_);
        float d0 = aP_[0]-aT_[0], d1 = aP_[1]-aT_[1], d2 = aP_[2]-aT_[2];
        loss += wf * (K_R1 * (d0*d0 + d1*d1 + d2*d2));
    }
    { // joint 1: parent identity; pos = offs[1] for both (shared p1)
        float aP_[6], aT_[6];
        read6f(pb9, 1, aP_); read6f(tb9, 1, aT_);
        float dsum = 0.f;
        #pragma unroll
        for (int k = 0; k < 6; ++k) { float dd = aP_[k]-aT_[k]; dsum += dd*dd; }
        loss += wf * (K_R2 * dsum);
        cont6d(aP_, R1P);
        cont6d(aT_, R1T);
        p1[0] = offs[3]; p1[1] = offs[4]; p1[2] = offs[5];
    }
    JS( 2, 2, true , true , false, R1, p1, RA, pA);   // spine

    // ---- stage 1: joints 3..5 (floats 18..36) ----
    SB; stage<9, 18>(pred, targ, rowbase, s0, lds, lane);
    JS( 3, 0, true , false, false, RA, pA, R3, p3);
    JS( 4, 1, true , false, false, R3, p3, RA, pA);
    JS( 5, 2, false, false, false, RA, pA, RB, pS);   // leaf

    // ---- stage 2: joints 6..8 (floats 36..54) ----
    SB; stage<9, 36>(pred, targ, rowbase, s0, lds, lane);
    JS( 6, 0, true , false, false, R3, p3, RA, pA);
    JS( 7, 1, true , false, false, RA, pA, RB, pB);
    JS( 8, 2, true , false, false, RB, pB, RA, pA);

    // ---- stage 3: joints 9..11 (floats 54..72) ----
    SB; stage<9, 54>(pred, targ, rowbase, s0, lds, lane);
    JS( 9, 0, false, false, false, RA, pA, RB, pS);   // leaf
    JS(10, 1, true , false, false, R3, p3, RB, pB);   // R3 dies
    JS(11, 2, true , false, false, RB, pB, RA, pA);

    // ---- stage 4: joints 12..14 (floats 72..90) ----
    SB; stage<9, 72>(pred, targ, rowbase, s0, lds, lane);
    JS(12, 0, true , false, false, RA, pA, RB, pB);
    JS(13, 1, false, false, false, RB, pB, RA, pS);   // leaf
    JS(14, 2, true , false, false, R1, p1, RA, pA);

    // ---- stage 5: joints 15..17 (floats 90..108) ----
    SB; stage<9, 90>(pred, targ, rowbase, s0, lds, lane);
    JS(15, 0, true , false, false, RA, pA, RB, pB);
    JS(16, 1, true , false, false, RB, pB, RA, pA);
    JS(17, 2, true , false, false, RA, pA, RB, pB);

    // ---- stage 6: joints 18..20 (floats 108..126) ----
    SB; stage<9, 108>(pred, targ, rowbase, s0, lds, lane);
    JS(18, 0, false, false, true , RB, pB, RA, pS);   // FOOT leaf
    JS(19, 1, true , false, false, R1, p1, RA, pA);   // R1 dies
    JS(20, 2, true , false, false, RA, pA, RB, pB);

    // ---- stage 7: joint 21 (floats 126..132, C2=3 layout) ----
    SB; stage<3, 126>(pred, targ, rowbase, s0, lds, lane);
    {
        const float2* pb3 = l2 + lane * 3;
        const float2* tb3 = l2 + 192 + lane * 3;
        float aP_[6], aT_[6];
        read6f(pb3, 0, aP_); read6f(tb3, 0, aT_);
        joint_step<false, false, true>(aP_, aT_, offs + 21*3,
            RBP, pBP, RAP, pSP, RBT, pBT, RAT, pST, wf, wv, wa, loss);  // FOOT leaf
    }
    #undef JS
    #undef SB

    // wave butterfly reduce; one atomic per wave, spread over 64 slots
    float v = loss;
    #pragma unroll
    for (int o = 32; o > 0; o >>= 1) v += __shfl_xor(v, o);
    if (lane == 0) atomicAdd(&acc[cg & (NSLOT - 1)], v);
}

__global__ void finalize_kernel(const float* __restrict__ acc, float* __restrict__ out) {
    float v = acc[threadIdx.x];
    #pragma unroll
    for (int o = 32; o > 0; o >>= 1) v += __shfl_xor(v, o);
    if (threadIdx.x == 0) out[0] = v;
}

} // namespace

extern "C" void kernel_launch(void* const* d_in, const int* in_sizes, int n_in,
                              void* d_out, int out_size, void* d_ws, size_t ws_size,
                              hipStream_t stream) {
    const float* pred = (const float*)d_in[0];
    const float* targ = (const float*)d_in[1];
    const float* offs = (const float*)d_in[2];
    float* acc = (float*)d_ws;

    hipMemsetAsync(acc, 0, NSLOT * sizeof(float), stream);
    motion_loss_kernel<<<dim3(kB * NCHUNK), dim3(64), 0, stream>>>(pred, targ, offs, acc);
    finalize_kernel<<<1, 64, 0, stream>>>(acc, (float*)d_out);
}

// Round 20
// 62.619 us; speedup vs baseline: 1.3148x; 1.0334x over previous
//
#include <hip/hip_runtime.h>

namespace {

constexpr int kB = 256;
constexpr int kS = 512;
constexpr int CHUNK  = 62;                        // useful frames per wave (lane = frame, 2 overlap)
constexpr int NCHUNK = 9;                         // ceil(512/62)
constexpr int NSLOT  = 64;
constexpr int BUFF   = 1536;                      // floats per ring buffer (6144 B)
constexpr int LDSF   = 3 * BUFF;                  // 18432 B -> 8 WG/CU

// lambda / count literals -- single-count (each frame term computed ONCE).
constexpr float BSf   = 131072.f;                 // kB*kS
constexpr float K_R1  = 5.0f / (BSf * 3.f);
constexpr float K_R2  = 5.0f / (BSf * 6.f);
constexpr float K_ROT = 1.0f / (BSf * 120.f);
constexpr float K_POS = 2.0f / (BSf * 66.f);
constexpr float K_VEL = 1.0f / (256.f * 511.f * 66.f);
constexpr float K_SMO = 0.5f / (256.f * 510.f * 66.f);
constexpr float K_FLO = 2.0f / (BSf * 2.f);
constexpr float K_CON = 2.0f / (256.f * 511.f * 2.f);
constexpr float K_TIL = 1.0f / (BSf * 3.f);

__device__ __forceinline__ void cont6d(const float a[6], float R[3][3]) {
    float n1 = a[0]*a[0] + a[1]*a[1] + a[2]*a[2];
    float i1 = __frsqrt_rn(fmaxf(n1, 1e-24f));
    float b1x = a[0]*i1, b1y = a[1]*i1, b1z = a[2]*i1;
    float dp  = b1x*a[3] + b1y*a[4] + b1z*a[5];
    float ux = a[3] - b1x*dp, uy = a[4] - b1y*dp, uz = a[5] - b1z*dp;
    float n2 = ux*ux + uy*uy + uz*uz;
    float i2 = __frsqrt_rn(fmaxf(n2, 1e-24f));
    float b2x = ux*i2, b2y = uy*i2, b2z = uz*i2;
    R[0][0] = b1x; R[1][0] = b1y; R[2][0] = b1z;
    R[0][1] = b2x; R[1][1] = b2y; R[2][1] = b2z;
    R[0][2] = b1y*b2z - b1z*b2y;
    R[1][2] = b1z*b2x - b1x*b2z;
    R[2][2] = b1x*b2y - b1y*b2x;
}

// One FK joint, BOTH skeletons in-lane (r19-proven body).
template<bool NEED_R, bool SPINE_J, bool FOOT>
__device__ __forceinline__ void joint_step(
    const float aP[6], const float aT[6], const float* __restrict__ off,
    const float RpP[3][3], const float ppP[3], float RnP[3][3], float pnP[3],
    const float RpT[3][3], const float ppT[3], float RnT[3][3], float pnT[3],
    float wf, float wv, float wa, float& s)
{
    float dsum = 0.f;
    #pragma unroll
    for (int k = 0; k < 6; ++k) { float dd = aP[k] - aT[k]; dsum += dd*dd; }
    s += wf * (K_ROT * dsum);

    const float ox = off[0], oy = off[1], oz = off[2];
    #pragma unroll
    for (int r = 0; r < 3; ++r) {
        pnP[r] = ppP[r] + RpP[r][0]*ox + RpP[r][1]*oy + RpP[r][2]*oz;
        pnT[r] = ppT[r] + RpT[r][0]*ox + RpT[r][1]*oy + RpT[r][2]*oz;
    }

    if constexpr (NEED_R) {
        float RlP[3][3], RlT[3][3];
        cont6d(aP, RlP);
        cont6d(aT, RlT);
        if constexpr (SPINE_J) {
            float t0 = RlP[0][1] - RlT[0][1];
            float t1 = RlP[1][1] - RlT[1][1];
            float t2 = RlP[2][1] - RlT[2][1];
            s += wf * (K_TIL * (t0*t0 + t1*t1 + t2*t2));
        }
        #pragma unroll
        for (int r = 0; r < 3; ++r)
            #pragma unroll
            for (int c = 0; c < 3; ++c) {
                RnP[r][c] = RpP[r][0]*RlP[0][c] + RpP[r][1]*RlP[1][c] + RpP[r][2]*RlP[2][c];
                RnT[r][c] = RpT[r][0]*RlT[0][c] + RpT[r][1]*RlT[1][c] + RpT[r][2]*RlT[2][c];
            }
    }

    float d[3], d1[3];
    #pragma unroll
    for (int r = 0; r < 3; ++r) d[r] = pnP[r] - pnT[r];
    s += wf * (K_POS * (d[0]*d[0] + d[1]*d[1] + d[2]*d[2]));

    float va = 0.f, sa = 0.f;
    #pragma unroll
    for (int r = 0; r < 3; ++r) {
        d1[r]    = __shfl_down(d[r], 1);
        float d2 = __shfl_down(d[r], 2);
        float dv = d1[r] - d[r];            va += dv*dv;
        float ds = d2 - 2.f*d1[r] + d[r];   sa += ds*ds;
    }
    s += wv * (K_VEL * va);
    s += wa * (K_SMO * sa);

    if constexpr (FOOT) {
        s += wf * (K_FLO * (d[1]*d[1]));
        float gx = __shfl_down(pnT[0], 1) - pnT[0];   // gt foot velocity
        float gy = __shfl_down(pnT[1], 1) - pnT[1];
        float gz = __shfl_down(pnT[2], 1) - pnT[2];
        float pvx = gx + (d1[0] - d[0]);              // pred vel = gt vel + delta-d
        float pvy = gy + (d1[1] - d[1]);
        float pvz = gz + (d1[2] - d[2]);
        float planted = (gx*gx + gy*gy + gz*gz < 2.5e-5f) ? 1.f : 0.f;
        s += wv * (K_CON * (planted * sqrtf(pvx*pvx + pvy*pvy + pvz*pvz)));
    }
}

// Async DMA staging (T3/T4): 11 stages x 2 joints, ring-3 LDS, counted vmcnt.
// DMA dest is wave-uniform base + lane*16 (forced-linear) -> LDS float4 index
// t*192 + f*3 + c  ==  [tensor][frame][c] (48 B/frame/stage), matching the
// per-lane read bases. Loads for stage k+1..k+3 stay in flight across stage
// k's compute -- per-wave in-flight bytes rise ~4x and persist (MLP fix).
__global__ __launch_bounds__(64)
void motion_loss_kernel(const float* __restrict__ pred,
                        const float* __restrict__ targ,
                        const float* __restrict__ offs,
                        float* __restrict__ acc)
{
    __shared__ float lds[LDSF];

    const int lane = threadIdx.x;       // lane = frame-in-chunk
    const int cg    = blockIdx.x;                 // 0..2303
    const int b     = cg / NCHUNK;
    const int chunk = cg - b * NCHUNK;
    const int s0    = chunk * CHUNK;
    const int s     = s0 + lane;

    const float wf = (lane < CHUNK && s     < kS) ? 1.f : 0.f;
    const float wv = (lane < CHUNK && s + 1 < kS) ? 1.f : 0.f;
    const float wa = (lane < CHUNK && s + 2 < kS) ? 1.f : 0.f;

    const float* predb = pred + (size_t)b * kS * 132;
    const float* targb = targ + (size_t)b * kS * 132;

    // issue one stage's 6 DMA loads (1 KB each): FB = first float of stage
    auto issue = [&](int FB, float* buf) {
        #pragma unroll
        for (int r = 0; r < 6; ++r) {
            const float* tb = (r < 3) ? predb : targb;
            int uu = (r % 3) * 64 + lane;            // 0..191
            int f  = uu / 3;                          // magic-mul
            int c  = uu - f * 3;
            int sf = s0 + f; sf = (sf < kS) ? sf : (kS - 1);
            const float* src = tb + (size_t)sf * 132 + FB + 4 * c;
            __builtin_amdgcn_global_load_lds(
                (const __attribute__((address_space(1))) void*)src,
                (__attribute__((address_space(3))) void*)(buf + r * 256),
                16, 0, 0);
        }
    };

    float* buf0 = lds;
    float* buf1 = lds + BUFF;
    float* buf2 = lds + 2 * BUFF;

    #define VW(N) do { asm volatile("s_waitcnt vmcnt(" #N ")" ::: "memory"); \
                       __builtin_amdgcn_sched_barrier(0); } while (0)
    #define LW0   do { asm volatile("s_waitcnt lgkmcnt(0)" ::: "memory"); \
                       __builtin_amdgcn_sched_barrier(0); } while (0)

    auto rd6 = [&](const float* base, int jj, float a[6]) {
        const float2* q = reinterpret_cast<const float2*>(base + jj * 6);
        float2 x = q[0], y = q[1], z = q[2];
        a[0]=x.x; a[1]=x.y; a[2]=y.x; a[3]=y.y; a[4]=z.x; a[5]=z.y;
    };

    // prologue: 3 stages in flight (18 loads)
    issue(0,  buf0);    // S0: j0,j1
    issue(12, buf1);    // S1: j2,j3
    issue(24, buf2);    // S2: j4,j5

    float loss = 0.f;
    float R1P[3][3], R3P[3][3], RAP[3][3], RBP[3][3];
    float R1T[3][3], R3T[3][3], RAT[3][3], RBT[3][3];
    float p1[3], p3P[3], pAP[3], pBP[3], pSP[3];
    float          p3T[3], pAT[3], pBT[3], pST[3];
    auto& p1P = p1; auto& p1T = p1;

    #define RD2(BUF) float aP0[6], aT0[6], aP1[6], aT1[6]; { \
        const float* pb_ = (BUF) + lane * 12; \
        const float* tb_ = (BUF) + 768 + lane * 12; \
        rd6(pb_, 0, aP0); rd6(tb_, 0, aT0); rd6(pb_, 1, aP1); rd6(tb_, 1, aT1); }

    #define JS(AP, AT, J, NR, SP, FT, RP, PP, RN, PN) \
        joint_step<NR, SP, FT>(AP, AT, offs + (J)*3, \
            RP##P, PP##P, RN##P, PN##P, RP##T, PP##T, RN##T, PN##T, \
            wf, wv, wa, loss)

    // ---- S0: joints 0,1 (special) ----
    VW(12);
    {
        RD2(buf0);
        LW0; issue(36, buf0);                         // S3: j6,j7
        { // joint 0: root channels 0..2 (in-lane diff); positions identically 0
            float d0 = aP0[0]-aT0[0], d1 = aP0[1]-aT0[1], d2 = aP0[2]-aT0[2];
            loss += wf * (K_R1 * (d0*d0 + d1*d1 + d2*d2));
        }
        { // joint 1: parent identity; pos = offs[1] for both (shared p1)
            float dsum = 0.f;
            #pragma unroll
            for (int k = 0; k < 6; ++k) { float dd = aP1[k]-aT1[k]; dsum += dd*dd; }
            loss += wf * (K_R2 * dsum);
            cont6d(aP1, R1P);
            cont6d(aT1, R1T);
            p1[0] = offs[3]; p1[1] = offs[4]; p1[2] = offs[5];
        }
    }
    // ---- S1: j2 (spine), j3 (save R3) ----
    VW(12);
    {
        RD2(buf1);
        LW0; issue(48, buf1);                         // S4: j8,j9
        JS(aP0, aT0,  2, true , true , false, R1, p1, RA, pA);
        JS(aP1, aT1,  3, true , false, false, RA, pA, R3, p3);
    }
    // ---- S2: j4, j5(leaf) ----
    VW(12);
    {
        RD2(buf2);
        LW0; issue(60, buf2);                         // S5: j10,j11
        JS(aP0, aT0,  4, true , false, false, R3, p3, RA, pA);
        JS(aP1, aT1,  5, false, false, false, RA, pA, RB, pS);
    }
    // ---- S3: j6, j7 ----
    VW(12);
    {
        RD2(buf0);
        LW0; issue(72, buf0);                         // S6: j12,j13
        JS(aP0, aT0,  6, true , false, false, R3, p3, RA, pA);
        JS(aP1, aT1,  7, true , false, false, RA, pA, RB, pB);
    }
    // ---- S4: j8, j9(leaf) ----
    VW(12);
    {
        RD2(buf1);
        LW0; issue(84, buf1);                         // S7: j14,j15
        JS(aP0, aT0,  8, true , false, false, RB, pB, RA, pA);
        JS(aP1, aT1,  9, false, false, false, RA, pA, RB, pS);
    }
    // ---- S5: j10 (R3 dies), j11 ----
    VW(12);
    {
        RD2(buf2);
        LW0; issue(96, buf2);                         // S8: j16,j17
        JS(aP0, aT0, 10, true , false, false, R3, p3, RB, pB);
        JS(aP1, aT1, 11, true , false, false, RB, pB, RA, pA);
    }
    // ---- S6: j12, j13(leaf) ----
    VW(12);
    {
        RD2(buf0);
        LW0; issue(108, buf0);                        // S9: j18,j19
        JS(aP0, aT0, 12, true , false, false, RA, pA, RB, pB);
        JS(aP1, aT1, 13, false, false, false, RB, pB, RA, pS);
    }
    // ---- S7: j14, j15 ----
    VW(12);
    {
        RD2(buf1);
        LW0; issue(120, buf1);                        // S10: j20,j21
        JS(aP0, aT0, 14, true , false, false, R1, p1, RA, pA);
        JS(aP1, aT1, 15, true , false, false, RA, pA, RB, pB);
    }
    // ---- S8: j16, j17 (no more issues) ----
    VW(12);
    {
        RD2(buf2);
        JS(aP0, aT0, 16, true , false, false, RB, pB, RA, pA);
        JS(aP1, aT1, 17, true , false, false, RA, pA, RB, pB);
    }
    // ---- S9: j18(FOOT), j19 (R1 dies) ----
    VW(6);
    {
        RD2(buf0);
        JS(aP0, aT0, 18, false, false, true , RB, pB, RA, pS);
        JS(aP1, aT1, 19, true , false, false, R1, p1, RA, pA);
    }
    // ---- S10: j20, j21(FOOT) ----
    VW(0);
    {
        RD2(buf1);
        JS(aP0, aT0, 20, true , false, false, RA, pA, RB, pB);
        JS(aP1, aT1, 21, false, false, true , RB, pB, RA, pS);
    }
    #undef JS
    #undef RD2
    #undef VW
    #undef LW0

    // wave butterfly reduce; one atomic per wave, spread over 64 slots
    float v = loss;
    #pragma unroll
    for (int o = 32; o > 0; o >>= 1) v += __shfl_xor(v, o);
    if (lane == 0) atomicAdd(&acc[cg & (NSLOT - 1)], v);
}

__global__ void finalize_kernel(const float* __restrict__ acc, float* __restrict__ out) {
    float v = acc[threadIdx.x];
    #pragma unroll
    for (int o = 32; o > 0; o >>= 1) v += __shfl_xor(v, o);
    if (threadIdx.x == 0) out[0] = v;
}

} // namespace

extern "C" void kernel_launch(void* const* d_in, const int* in_sizes, int n_in,
                              void* d_out, int out_size, void* d_ws, size_t ws_size,
                              hipStream_t stream) {
    const float* pred = (const float*)d_in[0];
    const float* targ = (const float*)d_in[1];
    const float* offs = (const float*)d_in[2];
    float* acc = (float*)d_ws;

    hipMemsetAsync(acc, 0, NSLOT * sizeof(float), stream);
    motion_loss_kernel<<<dim3(kB * NCHUNK), dim3(64), 0, stream>>>(pred, targ, offs, acc);
    finalize_kernel<<<1, 64, 0, stream>>>(acc, (float*)d_out);
}